// Round 4
// baseline (1650.063 us; speedup 1.0000x reference)
//
#include <hip/hip_runtime.h>
#include <hip/hip_bf16.h>

#define HLAT 181
#define WLON 360
#define HW (HLAT * WLON)
#define HPAD 188
#define WPAD 368
#define PPLANE ((size_t)HPAD * WPAD * 128)   // ushorts per plane

typedef __attribute__((ext_vector_type(8)))  short short8v;
typedef __attribute__((ext_vector_type(16))) float f32x16;

static __device__ __forceinline__ ushort bf16_hi_bits(float f) {
  union { float f; unsigned u; } c; c.f = f;
  unsigned u = c.u;
  unsigned rounded = u + 0x7FFF + ((u >> 16) & 1);  // RNE
  return (ushort)(rounded >> 16);
}
static __device__ __forceinline__ float bf16_to_f(ushort b) {
  union { unsigned u; float f; } c; c.u = ((unsigned)b) << 16;
  return c.f;
}

// ---------------- kernel 0: weight prep ----------------
// w2f: ushort array, entry order ((((tap*8+ch)*2+m)*2+p)*64+l)*8+j
//   value = part{hi,lo} of w2[oc=m*32+(l&31)][ci=ch*16+(l>>5)*8+j][tap]
__global__ __launch_bounds__(256) void k_tw(const float* __restrict__ w2,
                                            const float* __restrict__ w3,
                                            ushort* __restrict__ w2f,
                                            float* __restrict__ w3t) {
  int idx = blockIdx.x * 256 + threadIdx.x;
  if (idx < 51200) {
    int l   = idx & 63;
    int p   = (idx >> 6) & 1;
    int m   = (idx >> 7) & 1;
    int ch  = (idx >> 8) & 7;
    int tap = idx >> 11;
    int oc  = m * 32 + (l & 31);
    int ci0 = ch * 16 + (l >> 5) * 8;
#pragma unroll
    for (int j = 0; j < 8; ++j) {
      float f = w2[(oc * 128 + ci0 + j) * 25 + tap];
      ushort hi = bf16_hi_bits(f);
      ushort v;
      if (p == 0) v = hi;
      else        v = bf16_hi_bits(f - bf16_to_f(hi));
      w2f[(size_t)idx * 8 + j] = v;
    }
  }
  if (idx < 1600 * 4) {
    int ck = idx >> 2, o = idx & 3;
    int c = ck / 25, ij = ck % 25;
    w3t[idx] = (o < 3) ? w3[(o * 64 + c) * 25 + ij] : 0.f;
  }
}

// ---------------- zero the pad ring of the bf16 planes ----------------
__global__ __launch_bounds__(256) void k_zpad(ushort* __restrict__ h1s) {
  int px = blockIdx.x * 256 + threadIdx.x;
  if (px >= HPAD * WPAD) return;
  int yi = px / WPAD, xi = px % WPAD;
  if (yi >= 2 && yi <= 182 && xi >= 2 && xi <= 361) return;  // interior
  short8v z = {0, 0, 0, 0, 0, 0, 0, 0};
  short8v* d = (short8v*)(h1s + (size_t)blockIdx.y * PPLANE + (size_t)px * 128);
#pragma unroll
  for (int i = 0; i < 16; ++i) d[i] = z;
}

// ---------------- kernel 1: disco conv + w1 GEMM + relu -> split planes --
// planes: h1s[(bi*2+part)*PPLANE], layout [yi][xi][128ci] ushort (bf16)
__global__ __launch_bounds__(192) void k_l1(const float* __restrict__ x,
    const float* __restrict__ psi, const float* __restrict__ quad,
    const float* __restrict__ w1, const float* __restrict__ b1,
    ushort* __restrict__ h1s, int b0) {
  const int h = blockIdx.x;
  const int bi = blockIdx.y;
  const int b = b0 + bi;
  __shared__ __align__(16) float s_w1[128][28];
  __shared__ float s_psi[9][25];
  __shared__ float s_b1[128];
  const int tid = threadIdx.x;
  for (int idx = tid; idx < 128 * 27; idx += 192) s_w1[idx / 27][idx % 27] = w1[idx];
  for (int idx = tid; idx < 225; idx += 192)
    s_psi[idx / 25][idx % 25] = psi[(idx / 25) * (HLAT * 25) + h * 25 + (idx % 25)];
  if (tid < 128) { s_w1[tid][27] = 0.f; s_b1[tid] = b1[tid]; }
  __syncthreads();
  if (tid >= 180) return;

  float z[2][28];
#pragma unroll
  for (int q = 0; q < 28; ++q) { z[0][q] = 0.f; z[1][q] = 0.f; }

#pragma unroll
  for (int c = 0; c < 3; ++c) {
#pragma unroll
    for (int i = 0; i < 5; ++i) {
      int hi = h + i - 2;
      hi = hi < 0 ? 0 : (hi >= HLAT ? HLAT - 1 : hi);
      const float qv = quad[hi];
      const float* row = x + ((size_t)(b * 3 + c) * HLAT + hi) * WLON;
      float v0[5], v1[5];
#pragma unroll
      for (int j = 0; j < 5; ++j) {
        int wj0 = tid + j - 2; wj0 = wj0 < 0 ? wj0 + WLON : wj0;
        int wj1 = tid + 180 + j - 2; wj1 = wj1 >= WLON ? wj1 - WLON : wj1;
        v0[j] = row[wj0] * qv;
        v1[j] = row[wj1] * qv;
      }
#pragma unroll
      for (int k = 0; k < 9; ++k) {
        float a0 = 0.f, a1 = 0.f;
#pragma unroll
        for (int j = 0; j < 5; ++j) {
          const float p = s_psi[k][i * 5 + j];
          a0 += p * v0[j];
          a1 += p * v1[j];
        }
        z[0][c * 9 + k] += a0;
        z[1][c * 9 + k] += a1;
      }
    }
  }
  z[0][27] = 0.f; z[1][27] = 0.f;

  ushort* phi = h1s + (size_t)(bi * 2 + 0) * PPLANE;
  ushort* plo = h1s + (size_t)(bi * 2 + 1) * PPLANE;
  const size_t pix0 = ((size_t)(h + 2) * WPAD + (tid + 2)) * 128;
  const size_t pix1 = ((size_t)(h + 2) * WPAD + (tid + 180 + 2)) * 128;

  union { ushort u[8]; short8v v; } bh0, bl0, bh1, bl1;
  for (int o = 0; o < 128; ++o) {
    float a0 = s_b1[o], a1 = a0;
#pragma unroll
    for (int q4 = 0; q4 < 7; ++q4) {
      const float4 wv = *(const float4*)&s_w1[o][q4 * 4];
      a0 += wv.x * z[0][q4 * 4 + 0] + wv.y * z[0][q4 * 4 + 1] +
            wv.z * z[0][q4 * 4 + 2] + wv.w * z[0][q4 * 4 + 3];
      a1 += wv.x * z[1][q4 * 4 + 0] + wv.y * z[1][q4 * 4 + 1] +
            wv.z * z[1][q4 * 4 + 2] + wv.w * z[1][q4 * 4 + 3];
    }
    a0 = fmaxf(a0, 0.f); a1 = fmaxf(a1, 0.f);
    const int r = o & 7;
    ushort h0 = bf16_hi_bits(a0);
    ushort h1v = bf16_hi_bits(a1);
    bh0.u[r] = h0; bl0.u[r] = bf16_hi_bits(a0 - bf16_to_f(h0));
    bh1.u[r] = h1v; bl1.u[r] = bf16_hi_bits(a1 - bf16_to_f(h1v));
    if (r == 7) {
      *(short8v*)(phi + pix0 + o - 7) = bh0.v;
      *(short8v*)(plo + pix0 + o - 7) = bl0.v;
      *(short8v*)(phi + pix1 + o - 7) = bh1.v;
      *(short8v*)(plo + pix1 + o - 7) = bl1.v;
    }
  }
}

// ---------------- kernel 2: conv 128->64 via bf16x3 MFMA ------------------
// grid (3, 46, bc) block 256 (4 waves). Out tile: 64oc x 4rows x 120cols.
// Staging via global_load_lds from the padded split planes (no bounds checks).
__global__ __launch_bounds__(256, 2) void k_conv2(const ushort* __restrict__ h1s,
    const ushort* __restrict__ w2f, const float* __restrict__ b2,
    float* __restrict__ h2) {
  __shared__ ushort act[2][8][128][16];  // [part][row][col][ci16] = 64 KB
  const int x0 = blockIdx.x * 120;
  const int y0 = blockIdx.y * 4;
  const int bi = blockIdx.z;
  const int tid = threadIdx.x;
  const int wv = tid >> 6;
  const int l = tid & 63;
  const int l31 = l & 31;
  const int q = l >> 5;

  f32x16 acc[2][4];
#pragma unroll
  for (int m = 0; m < 2; ++m)
#pragma unroll
    for (int n = 0; n < 4; ++n)
#pragma unroll
      for (int r = 0; r < 16; ++r) acc[m][n][r] = 0.f;

  const short8v* wf = (const short8v*)w2f;
  const short8v* actp = (const short8v*)&act[0][0][0][0];
  const ushort* pbase = h1s + (size_t)(bi * 2) * PPLANE;

  for (int ch = 0; ch < 8; ++ch) {
    __syncthreads();   // previous chunk's readers done
    // ---- async stage: 16 global_load_lds (16B) per wave ----
#pragma unroll
    for (int s = 0; s < 16; ++s) {
      const int k = wv * 16 + s;       // 0..63 instr id
      const int part = k >> 5;         // 0..1
      const int row = (k >> 2) & 7;    // 0..7
      const int c0 = (k & 3) << 5;     // 0,32,64,96
      const ushort* g = pbase + (size_t)part * PPLANE +
          ((size_t)(y0 + row) * WPAD + (x0 + c0 + (l >> 1))) * 128 +
          ch * 16 + (l & 1) * 8;
      ushort* ldst = &act[part][row][c0][0];
      __builtin_amdgcn_global_load_lds(
          (const __attribute__((address_space(1))) unsigned int*)g,
          (__attribute__((address_space(3))) unsigned int*)ldst, 16, 0, 0);
    }
    asm volatile("s_waitcnt vmcnt(0)" ::: "memory");
    __syncthreads();   // all waves' loads landed
    // ---- compute: 25 taps, 5-tap scheduling windows ----
#pragma unroll 1
    for (int di = 0; di < 5; ++di) {
      const int row = wv + di;
#pragma unroll
      for (int dj = 0; dj < 5; ++dj) {
        const int tap = di * 5 + dj;
        const int e0 = ((tap * 8 + ch) * 2) * 2;
        short8v a0h = wf[(size_t)(e0 + 0) * 64 + l];
        short8v a0l = wf[(size_t)(e0 + 1) * 64 + l];
        short8v a1h = wf[(size_t)(e0 + 2) * 64 + l];
        short8v a1l = wf[(size_t)(e0 + 3) * 64 + l];
#pragma unroll
        for (int n = 0; n < 4; ++n) {
          int col = n * 32 + l31 + dj;
          col = col < 127 ? col : 127;       // in-bounds; pad cols are zero
          const int idxh = (row * 128 + col) * 2 + q;
          short8v bh = actp[idxh];
          short8v bl = actp[idxh + 2048];
          acc[0][n] = __builtin_amdgcn_mfma_f32_32x32x16_bf16(a0h, bh, acc[0][n], 0, 0, 0);
          acc[0][n] = __builtin_amdgcn_mfma_f32_32x32x16_bf16(a0l, bh, acc[0][n], 0, 0, 0);
          acc[0][n] = __builtin_amdgcn_mfma_f32_32x32x16_bf16(a0h, bl, acc[0][n], 0, 0, 0);
          acc[1][n] = __builtin_amdgcn_mfma_f32_32x32x16_bf16(a1h, bh, acc[1][n], 0, 0, 0);
          acc[1][n] = __builtin_amdgcn_mfma_f32_32x32x16_bf16(a1l, bh, acc[1][n], 0, 0, 0);
          acc[1][n] = __builtin_amdgcn_mfma_f32_32x32x16_bf16(a1h, bl, acc[1][n], 0, 0, 0);
        }
      }
    }
  }

  // ---- epilogue: bias + relu + store (strict ownership: npx < 120) ----
  const int y = y0 + wv;
  if (y < HLAT) {
#pragma unroll
    for (int m = 0; m < 2; ++m) {
#pragma unroll
      for (int r = 0; r < 16; ++r) {
        const int oc = m * 32 + (r & 3) + 8 * (r >> 2) + 4 * q;
        const float bb = b2[oc];
        float* dst = h2 + ((size_t)(bi * 64 + oc) * HLAT + y) * WLON;
#pragma unroll
        for (int n = 0; n < 4; ++n) {
          const int npx = n * 32 + l31;
          const int px = x0 + npx;
          if (npx < 120 && px < WLON)
            dst[px] = fmaxf(acc[m][n][r] + bb, 0.f);
        }
      }
    }
  }
}

// ---------------- kernel 3: conv 64->3, 5x5, zero pad (f32) ---------------
__global__ __launch_bounds__(256) void k_conv3(const float* __restrict__ h2,
    const float* __restrict__ w3t, const float* __restrict__ b3,
    float* __restrict__ out, int b0) {
  const int x0 = blockIdx.x * 128;
  const int y0 = blockIdx.y * 8;
  const int bi = blockIdx.z;
  __shared__ __align__(16) float s_w3[1600][4];
  __shared__ __align__(16) float s_in[4][12][136];
  const int tid = threadIdx.x;
  const int ry = tid >> 5;
  const int cx0 = (tid & 31) << 2;

  for (int idx = tid; idx < 1600; idx += 256)
    ((float4*)s_w3)[idx] = ((const float4*)w3t)[idx];

  float acc[3][4];
#pragma unroll
  for (int o = 0; o < 3; ++o)
#pragma unroll
    for (int p = 0; p < 4; ++p) acc[o][p] = 0.f;

  for (int cc = 0; cc < 16; ++cc) {
    __syncthreads();
    for (int idx = tid; idx < 4 * 12 * 132; idx += 256) {
      const int ci = idx / (12 * 132);
      const int r = (idx / 132) % 12;
      const int col = idx % 132;
      const int yy = y0 + r - 2;
      const int xx = x0 + col - 2;
      float v = 0.f;
      if (yy >= 0 && yy < HLAT && xx >= 0 && xx < WLON)
        v = h2[((size_t)(bi * 64 + cc * 4 + ci) * HLAT + yy) * WLON + xx];
      s_in[ci][r][col] = v;
    }
    __syncthreads();
#pragma unroll
    for (int ci = 0; ci < 4; ++ci) {
#pragma unroll
      for (int i = 0; i < 5; ++i) {
        const float4 a4 = *(const float4*)&s_in[ci][ry + i][cx0];
        const float4 b4 = *(const float4*)&s_in[ci][ry + i][cx0 + 4];
        const float win[8] = {a4.x, a4.y, a4.z, a4.w, b4.x, b4.y, b4.z, b4.w};
#pragma unroll
        for (int j = 0; j < 5; ++j) {
          const float4 w4 = *(const float4*)&s_w3[(cc * 4 + ci) * 25 + i * 5 + j][0];
          const float wv3[3] = {w4.x, w4.y, w4.z};
#pragma unroll
          for (int p = 0; p < 4; ++p) {
            const float v = win[j + p];
#pragma unroll
            for (int o = 0; o < 3; ++o) acc[o][p] += wv3[o] * v;
          }
        }
      }
    }
  }
  const int oy = y0 + ry;
  const int b = b0 + bi;
  if (oy < HLAT) {
#pragma unroll
    for (int o = 0; o < 3; ++o) {
      const float bb = b3[o];
      float* dst = out + ((size_t)(b * 3 + o) * HLAT + oy) * WLON;
#pragma unroll
      for (int p = 0; p < 4; ++p) {
        const int ox = x0 + cx0 + p;
        if (ox < WLON) dst[ox] = acc[o][p] + bb;
      }
    }
  }
}

extern "C" void kernel_launch(void* const* d_in, const int* in_sizes, int n_in,
                              void* d_out, int out_size, void* d_ws, size_t ws_size,
                              hipStream_t stream) {
  const float* x    = (const float*)d_in[0];
  const float* psi  = (const float*)d_in[1];
  const float* quad = (const float*)d_in[2];
  const float* w1   = (const float*)d_in[3];
  const float* b1   = (const float*)d_in[4];
  const float* w2   = (const float*)d_in[5];
  const float* b2   = (const float*)d_in[6];
  const float* w3   = (const float*)d_in[7];
  const float* b3   = (const float*)d_in[8];
  float* out = (float*)d_out;
  float* ws  = (float*)d_ws;

  float*  w3t = ws;                       // 6400 floats
  ushort* w2f = (ushort*)(ws + 6400);     // 409600 ushorts
  const size_t HEAD = 211200;             // floats

  size_t wsf = ws_size / 4;
  // per-batch: PPLANE floats (2 ushort planes) + 64*HW floats (h2)
  const size_t per_b = PPLANE + (size_t)64 * HW;
  int bc = 8;
  while (bc > 1 && HEAD + (size_t)bc * per_b > wsf) bc >>= 1;

  ushort* h1s = (ushort*)(ws + HEAD);                 // bc*2*PPLANE ushorts
  float*  h2  = ws + HEAD + (size_t)bc * PPLANE;      // bc*64*HW floats

  k_tw<<<dim3(200), dim3(256), 0, stream>>>(w2, w3, w2f, w3t);
  k_zpad<<<dim3((HPAD * WPAD + 255) / 256, bc * 2), dim3(256), 0, stream>>>(h1s);

  for (int b0 = 0; b0 < 8; b0 += bc) {
    int cur = 8 - b0 < bc ? 8 - b0 : bc;
    k_l1<<<dim3(HLAT, cur), dim3(192), 0, stream>>>(x, psi, quad, w1, b1, h1s, b0);
    k_conv2<<<dim3(3, 46, cur), dim3(256), 0, stream>>>(h1s, w2f, b2, h2);
    k_conv3<<<dim3(3, 23, cur), dim3(256), 0, stream>>>(h2, w3t, b3, out, b0);
  }
}

// Round 5
// 1450.446 us; speedup vs baseline: 1.1376x; 1.1376x over previous
//
#include <hip/hip_runtime.h>
#include <hip/hip_bf16.h>

#define HLAT 181
#define WLON 360
#define HW (HLAT * WLON)
#define HPAD 188
#define WPAD 368
#define PCH ((size_t)HPAD * WPAD * 16)   // ushorts per chunk-plane

typedef __attribute__((ext_vector_type(8)))  short short8v;
typedef __attribute__((ext_vector_type(16))) float f32x16;

static __device__ __forceinline__ ushort bf16_hi_bits(float f) {
  union { float f; unsigned u; } c; c.f = f;
  unsigned u = c.u;
  unsigned rounded = u + 0x7FFF + ((u >> 16) & 1);  // RNE
  return (ushort)(rounded >> 16);
}
static __device__ __forceinline__ float bf16_to_f(ushort b) {
  union { unsigned u; float f; } c; c.u = ((unsigned)b) << 16;
  return c.f;
}

// ---------------- kernel 0: weight prep ----------------
// w2f entry idx = (tap*8+ch)*4 + m*2 + p ; each entry = 64 short8 (lane l)
//   lane l, j: part p of w2[oc=m*32+(l&31)][ci=ch*16+(l>>5)*8+j][tap]
__global__ __launch_bounds__(256) void k_tw(const float* __restrict__ w2,
                                            const float* __restrict__ w3,
                                            ushort* __restrict__ w2f,
                                            float* __restrict__ w3t) {
  int idx = blockIdx.x * 256 + threadIdx.x;
  if (idx < 51200) {
    int l   = idx & 63;
    int p   = (idx >> 6) & 1;
    int m   = (idx >> 7) & 1;
    int ch  = (idx >> 8) & 7;
    int tap = idx >> 11;
    int oc  = m * 32 + (l & 31);
    int ci0 = ch * 16 + (l >> 5) * 8;
#pragma unroll
    for (int j = 0; j < 8; ++j) {
      float f = w2[(oc * 128 + ci0 + j) * 25 + tap];
      ushort hi = bf16_hi_bits(f);
      ushort v;
      if (p == 0) v = hi;
      else        v = bf16_hi_bits(f - bf16_to_f(hi));
      w2f[(size_t)idx * 8 + j] = v;
    }
  }
  if (idx < 1600 * 4) {
    int ck = idx >> 2, o = idx & 3;
    int c = ck / 25, ij = ck % 25;
    w3t[idx] = (o < 3) ? w3[(o * 64 + c) * 25 + ij] : 0.f;
  }
}

// ---------------- zero the pad ring of each chunk-plane ----------------
__global__ __launch_bounds__(256) void k_zpad(ushort* __restrict__ h1s) {
  int px = blockIdx.x * 256 + threadIdx.x;
  if (px >= HPAD * WPAD) return;
  int yi = px / WPAD, xi = px % WPAD;
  if (yi >= 2 && yi <= 182 && xi >= 2 && xi <= 361) return;  // interior
  short8v z = {0, 0, 0, 0, 0, 0, 0, 0};
  short8v* d = (short8v*)(h1s + (size_t)blockIdx.y * PCH + (size_t)px * 16);
  d[0] = z; d[1] = z;
}

// ---------------- kernel 1: disco conv + w1 GEMM + relu -> chunk planes --
// h1s plane index: (bi*2+part)*8 + ch ; layout [yi][xi][16ci] (bf16 bits)
__global__ __launch_bounds__(192) void k_l1(const float* __restrict__ x,
    const float* __restrict__ psi, const float* __restrict__ quad,
    const float* __restrict__ w1, const float* __restrict__ b1,
    ushort* __restrict__ h1s, int b0) {
  const int h = blockIdx.x;
  const int bi = blockIdx.y;
  const int b = b0 + bi;
  __shared__ __align__(16) float s_w1[128][28];
  __shared__ float s_psi[9][25];
  __shared__ float s_b1[128];
  const int tid = threadIdx.x;
  for (int idx = tid; idx < 128 * 27; idx += 192) s_w1[idx / 27][idx % 27] = w1[idx];
  for (int idx = tid; idx < 225; idx += 192)
    s_psi[idx / 25][idx % 25] = psi[(idx / 25) * (HLAT * 25) + h * 25 + (idx % 25)];
  if (tid < 128) { s_w1[tid][27] = 0.f; s_b1[tid] = b1[tid]; }
  __syncthreads();
  if (tid >= 180) return;

  float z[2][28];
#pragma unroll
  for (int q = 0; q < 28; ++q) { z[0][q] = 0.f; z[1][q] = 0.f; }

#pragma unroll
  for (int c = 0; c < 3; ++c) {
#pragma unroll
    for (int i = 0; i < 5; ++i) {
      int hi = h + i - 2;
      hi = hi < 0 ? 0 : (hi >= HLAT ? HLAT - 1 : hi);
      const float qv = quad[hi];
      const float* row = x + ((size_t)(b * 3 + c) * HLAT + hi) * WLON;
      float v0[5], v1[5];
#pragma unroll
      for (int j = 0; j < 5; ++j) {
        int wj0 = tid + j - 2; wj0 = wj0 < 0 ? wj0 + WLON : wj0;
        int wj1 = tid + 180 + j - 2; wj1 = wj1 >= WLON ? wj1 - WLON : wj1;
        v0[j] = row[wj0] * qv;
        v1[j] = row[wj1] * qv;
      }
#pragma unroll
      for (int k = 0; k < 9; ++k) {
        float a0 = 0.f, a1 = 0.f;
#pragma unroll
        for (int j = 0; j < 5; ++j) {
          const float p = s_psi[k][i * 5 + j];
          a0 += p * v0[j];
          a1 += p * v1[j];
        }
        z[0][c * 9 + k] += a0;
        z[1][c * 9 + k] += a1;
      }
    }
  }
  z[0][27] = 0.f; z[1][27] = 0.f;

  ushort* base = h1s + (size_t)bi * 16 * PCH;
  const size_t poff0 = ((size_t)(h + 2) * WPAD + (tid + 2)) * 16;
  const size_t poff1 = ((size_t)(h + 2) * WPAD + (tid + 180 + 2)) * 16;

  for (int chv = 0; chv < 8; ++chv) {
    union { ushort u[16]; short8v v[2]; } h0b, l0b, h1b, l1b;
#pragma unroll
    for (int oo = 0; oo < 16; ++oo) {
      const int o = chv * 16 + oo;
      float a0 = s_b1[o], a1 = a0;
#pragma unroll
      for (int q4 = 0; q4 < 7; ++q4) {
        const float4 wv = *(const float4*)&s_w1[o][q4 * 4];
        a0 += wv.x * z[0][q4 * 4 + 0] + wv.y * z[0][q4 * 4 + 1] +
              wv.z * z[0][q4 * 4 + 2] + wv.w * z[0][q4 * 4 + 3];
        a1 += wv.x * z[1][q4 * 4 + 0] + wv.y * z[1][q4 * 4 + 1] +
              wv.z * z[1][q4 * 4 + 2] + wv.w * z[1][q4 * 4 + 3];
      }
      a0 = fmaxf(a0, 0.f); a1 = fmaxf(a1, 0.f);
      const ushort hb0 = bf16_hi_bits(a0);
      const ushort hb1 = bf16_hi_bits(a1);
      h0b.u[oo] = hb0; l0b.u[oo] = bf16_hi_bits(a0 - bf16_to_f(hb0));
      h1b.u[oo] = hb1; l1b.u[oo] = bf16_hi_bits(a1 - bf16_to_f(hb1));
    }
    ushort* phi = base + (size_t)chv * PCH;            // part 0
    ushort* plo = base + (size_t)(8 + chv) * PCH;      // part 1
    *(short8v*)(phi + poff0) = h0b.v[0]; *(short8v*)(phi + poff0 + 8) = h0b.v[1];
    *(short8v*)(plo + poff0) = l0b.v[0]; *(short8v*)(plo + poff0 + 8) = l0b.v[1];
    *(short8v*)(phi + poff1) = h1b.v[0]; *(short8v*)(phi + poff1 + 8) = h1b.v[1];
    *(short8v*)(plo + poff1) = l1b.v[0]; *(short8v*)(plo + poff1 + 8) = l1b.v[1];
  }
}

// ---------------- kernel 2: conv 128->64 via bf16x3 MFMA ------------------
// grid (3, 46, bc) block 256 (4 waves). Out tile: 64oc x 4rows x 120cols.
// Staging: 1KB-contiguous global_load_lds from chunk planes.
// Compute: per di-window, batch-issue 20 A-loads, then 120 MFMA.
__global__ __launch_bounds__(256, 2) void k_conv2(const ushort* __restrict__ h1s,
    const ushort* __restrict__ w2f, const float* __restrict__ b2,
    float* __restrict__ h2) {
  __shared__ ushort act[2][8][128][16];  // [part][row][col][ci16] = 64 KB
  const int x0 = blockIdx.x * 120;
  const int y0 = blockIdx.y * 4;
  const int bi = blockIdx.z;
  const int tid = threadIdx.x;
  const int wv = tid >> 6;
  const int l = tid & 63;
  const int l31 = l & 31;
  const int q = l >> 5;

  f32x16 acc[2][4];
#pragma unroll
  for (int m = 0; m < 2; ++m)
#pragma unroll
    for (int n = 0; n < 4; ++n)
#pragma unroll
      for (int r = 0; r < 16; ++r) acc[m][n][r] = 0.f;

  const short8v* wf = (const short8v*)w2f;
  const short8v* actp = (const short8v*)&act[0][0][0][0];
  const ushort* pbase = h1s + (size_t)bi * 16 * PCH;

  for (int ch = 0; ch < 8; ++ch) {
    __syncthreads();   // previous chunk's readers done
    // ---- async stage: 16 global_load_lds (16B x 64 lanes = 1KB each) ----
#pragma unroll
    for (int s = 0; s < 16; ++s) {
      const int k = wv * 16 + s;       // 0..63
      const int part = k >> 5;
      const int row = (k >> 2) & 7;
      const int c0 = (k & 3) << 5;
      const ushort* g = pbase + (size_t)(part * 8 + ch) * PCH +
          ((size_t)(y0 + row) * WPAD + (x0 + c0 + (l >> 1))) * 16 + (l & 1) * 8;
      ushort* ldst = &act[part][row][c0][0];
      __builtin_amdgcn_global_load_lds(
          (const __attribute__((address_space(1))) unsigned int*)g,
          (__attribute__((address_space(3))) unsigned int*)ldst, 16, 0, 0);
    }
    asm volatile("s_waitcnt vmcnt(0)" ::: "memory");
    __syncthreads();   // all waves' loads landed
    // ---- compute: 5 di-windows of 5 taps ----
#pragma unroll 1
    for (int di = 0; di < 5; ++di) {
      const int row = wv + di;
      short8v aw[5][4];
#pragma unroll
      for (int dj = 0; dj < 5; ++dj) {
        const size_t e0 = (size_t)(((di * 5 + dj) * 8 + ch) * 4) * 64 + l;
        aw[dj][0] = wf[e0];
        aw[dj][1] = wf[e0 + 64];
        aw[dj][2] = wf[e0 + 128];
        aw[dj][3] = wf[e0 + 192];
      }
      __builtin_amdgcn_s_setprio(1);
#pragma unroll
      for (int dj = 0; dj < 5; ++dj) {
#pragma unroll
        for (int n = 0; n < 4; ++n) {
          int col = n * 32 + l31 + dj;
          col = col < 127 ? col : 127;       // in-bounds; pad cols are zero
          const int idxh = (row * 128 + col) * 2 + q;
          short8v bh = actp[idxh];
          short8v bl = actp[idxh + 2048];
          acc[0][n] = __builtin_amdgcn_mfma_f32_32x32x16_bf16(aw[dj][0], bh, acc[0][n], 0, 0, 0);
          acc[0][n] = __builtin_amdgcn_mfma_f32_32x32x16_bf16(aw[dj][1], bh, acc[0][n], 0, 0, 0);
          acc[0][n] = __builtin_amdgcn_mfma_f32_32x32x16_bf16(aw[dj][0], bl, acc[0][n], 0, 0, 0);
          acc[1][n] = __builtin_amdgcn_mfma_f32_32x32x16_bf16(aw[dj][2], bh, acc[1][n], 0, 0, 0);
          acc[1][n] = __builtin_amdgcn_mfma_f32_32x32x16_bf16(aw[dj][3], bh, acc[1][n], 0, 0, 0);
          acc[1][n] = __builtin_amdgcn_mfma_f32_32x32x16_bf16(aw[dj][2], bl, acc[1][n], 0, 0, 0);
        }
      }
      __builtin_amdgcn_s_setprio(0);
    }
  }

  // ---- epilogue: bias + relu + store (strict ownership: npx < 120) ----
  const int y = y0 + wv;
  if (y < HLAT) {
#pragma unroll
    for (int m = 0; m < 2; ++m) {
#pragma unroll
      for (int r = 0; r < 16; ++r) {
        const int oc = m * 32 + (r & 3) + 8 * (r >> 2) + 4 * q;
        const float bb = b2[oc];
        float* dst = h2 + ((size_t)(bi * 64 + oc) * HLAT + y) * WLON;
#pragma unroll
        for (int n = 0; n < 4; ++n) {
          const int npx = n * 32 + l31;
          const int px = x0 + npx;
          if (npx < 120 && px < WLON)
            dst[px] = fmaxf(acc[m][n][r] + bb, 0.f);
        }
      }
    }
  }
}

// ---------------- kernel 3: conv 64->3, 5x5, zero pad (f32) ---------------
__global__ __launch_bounds__(256) void k_conv3(const float* __restrict__ h2,
    const float* __restrict__ w3t, const float* __restrict__ b3,
    float* __restrict__ out, int b0) {
  const int x0 = blockIdx.x * 128;
  const int y0 = blockIdx.y * 8;
  const int bi = blockIdx.z;
  __shared__ __align__(16) float s_w3[1600][4];
  __shared__ __align__(16) float s_in[4][12][136];
  const int tid = threadIdx.x;
  const int ry = tid >> 5;
  const int cx0 = (tid & 31) << 2;

  for (int idx = tid; idx < 1600; idx += 256)
    ((float4*)s_w3)[idx] = ((const float4*)w3t)[idx];

  float acc[3][4];
#pragma unroll
  for (int o = 0; o < 3; ++o)
#pragma unroll
    for (int p = 0; p < 4; ++p) acc[o][p] = 0.f;

  for (int cc = 0; cc < 16; ++cc) {
    __syncthreads();
    for (int idx = tid; idx < 4 * 12 * 132; idx += 256) {
      const int ci = idx / (12 * 132);
      const int r = (idx / 132) % 12;
      const int col = idx % 132;
      const int yy = y0 + r - 2;
      const int xx = x0 + col - 2;
      float v = 0.f;
      if (yy >= 0 && yy < HLAT && xx >= 0 && xx < WLON)
        v = h2[((size_t)(bi * 64 + cc * 4 + ci) * HLAT + yy) * WLON + xx];
      s_in[ci][r][col] = v;
    }
    __syncthreads();
#pragma unroll
    for (int ci = 0; ci < 4; ++ci) {
#pragma unroll
      for (int i = 0; i < 5; ++i) {
        const float4 a4 = *(const float4*)&s_in[ci][ry + i][cx0];
        const float4 b4 = *(const float4*)&s_in[ci][ry + i][cx0 + 4];
        const float win[8] = {a4.x, a4.y, a4.z, a4.w, b4.x, b4.y, b4.z, b4.w};
#pragma unroll
        for (int j = 0; j < 5; ++j) {
          const float4 w4 = *(const float4*)&s_w3[(cc * 4 + ci) * 25 + i * 5 + j][0];
          const float wv3[3] = {w4.x, w4.y, w4.z};
#pragma unroll
          for (int p = 0; p < 4; ++p) {
            const float v = win[j + p];
#pragma unroll
            for (int o = 0; o < 3; ++o) acc[o][p] += wv3[o] * v;
          }
        }
      }
    }
  }
  const int oy = y0 + ry;
  const int b = b0 + bi;
  if (oy < HLAT) {
#pragma unroll
    for (int o = 0; o < 3; ++o) {
      const float bb = b3[o];
      float* dst = out + ((size_t)(b * 3 + o) * HLAT + oy) * WLON;
#pragma unroll
      for (int p = 0; p < 4; ++p) {
        const int ox = x0 + cx0 + p;
        if (ox < WLON) dst[ox] = acc[o][p] + bb;
      }
    }
  }
}

extern "C" void kernel_launch(void* const* d_in, const int* in_sizes, int n_in,
                              void* d_out, int out_size, void* d_ws, size_t ws_size,
                              hipStream_t stream) {
  const float* x    = (const float*)d_in[0];
  const float* psi  = (const float*)d_in[1];
  const float* quad = (const float*)d_in[2];
  const float* w1   = (const float*)d_in[3];
  const float* b1   = (const float*)d_in[4];
  const float* w2   = (const float*)d_in[5];
  const float* b2   = (const float*)d_in[6];
  const float* w3   = (const float*)d_in[7];
  const float* b3   = (const float*)d_in[8];
  float* out = (float*)d_out;
  float* ws  = (float*)d_ws;

  float*  w3t = ws;                       // 6400 floats
  ushort* w2f = (ushort*)(ws + 6400);     // 409600 ushorts
  const size_t HEAD = 211200;             // floats

  size_t wsf = ws_size / 4;
  const size_t h1s_f = PCH * 8;           // floats per batch for 16 chunk-planes
  const size_t per_b = h1s_f + (size_t)64 * HW;
  int bc = 8;
  while (bc > 1 && HEAD + (size_t)bc * per_b > wsf) bc >>= 1;

  ushort* h1s = (ushort*)(ws + HEAD);
  float*  h2  = ws + HEAD + (size_t)bc * h1s_f;

  k_tw<<<dim3(200), dim3(256), 0, stream>>>(w2, w3, w2f, w3t);
  k_zpad<<<dim3((HPAD * WPAD + 255) / 256, bc * 16), dim3(256), 0, stream>>>(h1s);

  for (int b0 = 0; b0 < 8; b0 += bc) {
    int cur = 8 - b0 < bc ? 8 - b0 : bc;
    k_l1<<<dim3(HLAT, cur), dim3(192), 0, stream>>>(x, psi, quad, w1, b1, h1s, b0);
    k_conv2<<<dim3(3, 46, cur), dim3(256), 0, stream>>>(h1s, w2f, b2, h2);
    k_conv3<<<dim3(3, 23, cur), dim3(256), 0, stream>>>(h2, w3t, b3, out, b0);
  }
}